// Round 4
// baseline (917.048 us; speedup 1.0000x reference)
//
#include <hip/hip_runtime.h>
#include <hip/hip_bf16.h>

// ---------------------------------------------------------------------------
// HypergraphConv x2 + PReLU + residual. R8: GEMM single-pass-A + packed part.
//   R7 post-mortem: gathers are at the 8-XCD compulsory fetch floor
//   (433MB vs 410MB = 8 x 51.2MB working set; uniformly random neighbors
//   make every XCD touch the whole matrix). Lever is the non-gather 272us:
//   - GEMM grid.y=2 staged each A panel twice (205MB/GEMM). Now grid.y=1,
//     wave covers 8 n-tiles (acc[4][8]); A read once.
//   - part entries packed int2 -> u32 (9b bucket-local key | 17b val),
//     halving partition write + fill read.
// Gathers/f16 intermediates unchanged (structural floor).
// ---------------------------------------------------------------------------

#define F_DIM 256
#define CAP 48          // padded adjacency slots per node; P(deg>=48)~1e-10
#define BW_SHIFT 9      // bucket width 512 nodes
#define CHUNK 2048      // edges per partition block

using bf16x8 = __attribute__((ext_vector_type(8))) short;
using f32x4  = __attribute__((ext_vector_type(4))) float;
using half4  = __attribute__((ext_vector_type(4))) _Float16;

__device__ __forceinline__ short f2bf(float f) {
    __hip_bfloat16 h = __float2bfloat16(f);
    return *reinterpret_cast<short*>(&h);
}
__device__ __forceinline__ float bf2f(short s) {
    return __uint_as_float(((unsigned)(unsigned short)s) << 16);
}

// ---- 1. bucket cursor init -------------------------------------------------
__global__ void init_cur_kernel(int* __restrict__ cur, int n, int buckcap) {
    int i = blockIdx.x * blockDim.x + threadIdx.x;
    if (i < n) cur[i] = i * buckcap;
}

// ---- 2. partition: edges -> bucket-grouped packed (key|val) ----------------
// grid (nchunks, 2): dir 0 keys=src (for adjS/degS), dir 1 keys=dst.
// entry = (val << 9) | (key & 511); val < 2^17, key&511 recovered in fill.
__global__ __launch_bounds__(256) void partition_kernel(
    const int* __restrict__ src, const int* __restrict__ dst,
    unsigned* __restrict__ part, int* __restrict__ cur,
    int nnz, int nb, int buckcap)
{
    __shared__ int lhist[256];
    __shared__ int lscan[256];
    __shared__ int gbase[256];
    __shared__ int sh_total;
    __shared__ unsigned lstage[CHUNK];   // 8 KB

    const int tid = threadIdx.x;
    const int dir = blockIdx.y;
    const int base = blockIdx.x * CHUNK;
    const int* __restrict__ key = dir ? dst : src;
    const int* __restrict__ val = dir ? src : dst;

    lhist[tid] = 0;
    __syncthreads();

    int myb[8], myr[8];
    unsigned mye[8];
#pragma unroll
    for (int i = 0; i < 8; ++i) {
        int g = base + tid + i * 256;
        myb[i] = -1;
        if (g < nnz) {
            int k = key[g];
            mye[i] = ((unsigned)val[g] << 9) | (unsigned)(k & 511);
            myb[i] = k >> BW_SHIFT;
            myr[i] = atomicAdd(&lhist[myb[i]], 1);   // LDS atomic: rank in block
        }
    }
    __syncthreads();

    // inclusive scan of per-bucket counts (Hillis-Steele over 256 bins)
    int v0 = lhist[tid];
    lscan[tid] = v0;
    __syncthreads();
    for (int off = 1; off < 256; off <<= 1) {
        int add = (tid >= off) ? lscan[tid - off] : 0;
        __syncthreads();
        lscan[tid] += add;
        __syncthreads();
    }
    int incl = lscan[tid];
    if (tid == 255) sh_total = incl;
    // reserve global space: one atomic per non-empty bucket per block
    if (tid < nb && v0 > 0) gbase[tid] = atomicAdd(&cur[dir * nb + tid], v0);
    __syncthreads();
    lscan[tid] = incl - v0;          // exclusive
    __syncthreads();

    // stage sorted-by-bucket in LDS (bucket id recoverable? no — pair with scan)
#pragma unroll
    for (int i = 0; i < 8; ++i)
        if (myb[i] >= 0)
            lstage[lscan[myb[i]] + myr[i]] = (mye[i] & ~0u) | 0u, // value
            lstage[lscan[myb[i]] + myr[i]] = mye[i];
    __syncthreads();

    // write out bucket runs. bucket of entry k = largest b with lscan[b] <= k;
    // recover via per-thread walk: iterate buckets, emit their runs.
    const int total = sh_total;
    for (int k = tid; k < total; k += 256) {
        // binary search bucket: find b such that lscan[b] <= k < lscan[b]+cnt[b]
        int lo = 0, hi = 255;
        while (lo < hi) {
            int mid = (lo + hi + 1) >> 1;
            if (lscan[mid] <= k) lo = mid; else hi = mid - 1;
        }
        int b = lo;
        int pos = gbase[b] + (k - lscan[b]);
        if (pos < (dir * nb + b + 1) * buckcap)   // overflow guard (never fires)
            part[pos] = lstage[k];
    }
}

// ---- 3. per-bucket fill: LDS per-node counters, L2-local adj writes --------
//         also emits deg[] and inverse-degree (Dinv/Binv) directly.
__global__ __launch_bounds__(256) void bucket_fill_kernel(
    const unsigned* __restrict__ part, const int* __restrict__ cur,
    int* __restrict__ adjS, int* __restrict__ adjD,
    int* __restrict__ degS, int* __restrict__ degD,
    float* __restrict__ Dinv, float* __restrict__ Binv,
    int M, int nb, int buckcap)
{
    __shared__ int lcnt[512];
    const int tid = threadIdx.x;
    const int b = blockIdx.x;
    const int dir = blockIdx.y;
    const int c = dir * nb + b;
    int* __restrict__ adj = dir ? adjD : adjS;
    int* __restrict__ deg = dir ? degD : degS;
    float* __restrict__ inv = dir ? Binv : Dinv;

    lcnt[tid] = 0;
    lcnt[tid + 256] = 0;
    __syncthreads();

    const int pbase = c * buckcap;
    const int cnt = min(cur[c] - pbase, buckcap);
    const int node0 = b << BW_SHIFT;
    for (int i = tid; i < cnt; i += 256) {
        unsigned e = part[pbase + i];
        int klocal = (int)(e & 511u);
        int v = (int)(e >> 9);
        int r = atomicAdd(&lcnt[klocal], 1);    // LDS atomic
        if (r < CAP) adj[(size_t)(node0 + klocal) * CAP + r] = v;
    }
    __syncthreads();
    for (int i = tid; i < 512; i += 256) {
        int node = node0 + i;
        if (node < M) {
            int d = min(lcnt[i], CAP);
            deg[node] = d;
            inv[node] = d > 0 ? 1.f / (float)d : 0.f;
        }
    }
}

// ---- 4. W prepack: f32 -> bf16 hi/lo MFMA B-fragment order -----------------
// frag blob (kt,nt): 64 lanes x 8; lane holds B[kt*32+(lane>>4)*8+j][nt*16+(lane&15)]
__global__ void prepack_w_kernel(const float* __restrict__ W,
                                 short* __restrict__ Whi, short* __restrict__ Wlo) {
    int lane = threadIdx.x;            // 64
    int nt = blockIdx.x;               // 16
    int kt = blockIdx.y;               // 8
    int col = nt * 16 + (lane & 15);
    int krow = kt * 32 + (lane >> 4) * 8;
    size_t o = ((size_t)(kt * 16 + nt) * 64 + lane) * 8;
#pragma unroll
    for (int j = 0; j < 8; ++j) {
        float w = W[(size_t)(krow + j) * 256 + col];
        short hi = f2bf(w);
        Whi[o + j] = hi;
        Wlo[o + j] = f2bf(w - bf2f(hi));
    }
}

// ---- 5. split-bf16 MFMA GEMM: C[M,256](f16) = A[M,256](f32) @ W ------------
// block 256 thr = 4 waves (2 in M x 2 in N); tile 128(M) x 256(N) -> A read
// ONCE. Wave tile 64x128 = acc[4][8]. K-loop 8x32.
__global__ __launch_bounds__(256, 2) void gemm_mfma_split(const float* __restrict__ A,
                                                          const short* __restrict__ Whi,
                                                          const short* __restrict__ Wlo,
                                                          _Float16* __restrict__ C, int M) {
    __shared__ short AsHi[4][128][8];    // 8 KB
    __shared__ short AsLo[4][128][8];    // 8 KB
    const int tid = threadIdx.x;
    const int w = tid >> 6, lane = tid & 63;
    const int quad = lane >> 4, l16 = lane & 15;
    const int bm = blockIdx.x * 128;
    const int wm = (w & 1) * 64;
    const int wnt = (w >> 1) * 8;                // 8 n-tiles (128 cols) per wave

    f32x4 acc[4][8] = {};

    for (int kt = 0; kt < 8; ++kt) {
        __syncthreads();
        // stage A tile: 128 rows x 32 k, f32 -> bf16 hi/lo
#pragma unroll
        for (int i = 0; i < 2; ++i) {
            int idx = tid + i * 256;
            int row = idx >> 2, seg = idx & 3;
            int grow = bm + row; if (grow >= M) grow = M - 1;
            const float* ap = A + (size_t)grow * 256 + kt * 32 + seg * 8;
            float4 v0 = *(const float4*)ap;
            float4 v1 = *(const float4*)(ap + 4);
            float vv[8] = {v0.x, v0.y, v0.z, v0.w, v1.x, v1.y, v1.z, v1.w};
            union { short s[8]; int4 q; } uh, ul;
#pragma unroll
            for (int e = 0; e < 8; ++e) {
                short hi = f2bf(vv[e]);
                uh.s[e] = hi;
                ul.s[e] = f2bf(vv[e] - bf2f(hi));
            }
            *(int4*)&AsHi[seg][row][0] = uh.q;
            *(int4*)&AsLo[seg][row][0] = ul.q;
        }
        __syncthreads();

        bf16x8 ahi[4], alo[4];
#pragma unroll
        for (int i = 0; i < 4; ++i) {
            ahi[i] = *(const bf16x8*)&AsHi[quad][wm + i * 16 + l16][0];
            alo[i] = *(const bf16x8*)&AsLo[quad][wm + i * 16 + l16][0];
        }

#pragma unroll
        for (int j = 0; j < 8; ++j) {
            int nt = wnt + j;
            size_t off = ((size_t)(kt * 16 + nt) * 64 + lane) * 8;
            bf16x8 bhi = *(const bf16x8*)(Whi + off);
            bf16x8 blo = *(const bf16x8*)(Wlo + off);
#pragma unroll
            for (int i = 0; i < 4; ++i) {
                acc[i][j] = __builtin_amdgcn_mfma_f32_16x16x32_bf16(ahi[i], bhi, acc[i][j], 0, 0, 0);
                acc[i][j] = __builtin_amdgcn_mfma_f32_16x16x32_bf16(ahi[i], blo, acc[i][j], 0, 0, 0);
                acc[i][j] = __builtin_amdgcn_mfma_f32_16x16x32_bf16(alo[i], bhi, acc[i][j], 0, 0, 0);
            }
        }
    }

    // epilogue: C[row][col] = (f16)acc; row = wm + i*16 + quad*4 + r
#pragma unroll
    for (int i = 0; i < 4; ++i) {
#pragma unroll
        for (int j = 0; j < 8; ++j) {
            int col = (wnt + j) * 16 + l16;
            int row0 = bm + wm + i * 16 + quad * 4;
#pragma unroll
            for (int r = 0; r < 4; ++r) {
                int row = row0 + r;
                if (row < M) C[(size_t)row * 256 + col] = (_Float16)acc[i][j][r];
            }
        }
    }
}

// ---- 6. pull gather: out[r] = f(scale[r]*sum_{j in adj[r]} src[j]) ---------
// src rows are f16 (512B). padded adjacency: row r at adj[r*CAP .. +deg[r]).
// OUT_F16=1 -> f16 output (xt->m hop); OUT_F16=0 -> f32 output (m->node hop).
template <int OUT_F16>
__global__ __launch_bounds__(256) void gather_rows_kernel(const _Float16* __restrict__ src_mat,
                                                          void* __restrict__ out_mat,
                                                          const int* __restrict__ deg,
                                                          const int* __restrict__ adj,
                                                          const float* __restrict__ scale,
                                                          const float* __restrict__ bias,
                                                          const float* __restrict__ residual,
                                                          const float* __restrict__ alpha_p,
                                                          int n) {
    int wid = (blockIdx.x * blockDim.x + threadIdx.x) >> 6;
    int lane = threadIdx.x & 63;
    if (wid >= n) return;
    const int dcount = deg[wid];                      // <= CAP (48) < 64
    const int* arow = adj + (size_t)wid * CAP;
    int myidx = (lane < dcount) ? __builtin_nontemporal_load(arow + lane) : 0;

    const size_t lo = (size_t)lane * 4;               // 4 f16 elems = 8B per lane
    float a0 = 0.f, a1 = 0.f, a2 = 0.f, a3 = 0.f;

    for (int j = 0; j < dcount; ++j) {
        int idx = __shfl(myidx, j);
        half4 v = *(const half4*)(src_mat + (size_t)idx * F_DIM + lo);
        a0 += (float)v.x; a1 += (float)v.y; a2 += (float)v.z; a3 += (float)v.w;
    }

    float sc = scale[wid];
    a0 *= sc; a1 *= sc; a2 *= sc; a3 *= sc;
    if (bias) {
        float4 bb = ((const float4*)bias)[lane];
        a0 += bb.x; a1 += bb.y; a2 += bb.z; a3 += bb.w;
    }
    if (residual) {
        const float* rp = residual + (size_t)wid * F_DIM + lo;
        float4 xv;
        xv.x = __builtin_nontemporal_load(rp + 0);
        xv.y = __builtin_nontemporal_load(rp + 1);
        xv.z = __builtin_nontemporal_load(rp + 2);
        xv.w = __builtin_nontemporal_load(rp + 3);
        a0 += xv.x; a1 += xv.y; a2 += xv.z; a3 += xv.w;
    }
    if (alpha_p) {
        float al = alpha_p[0];
        a0 = a0 >= 0.f ? a0 : al * a0;
        a1 = a1 >= 0.f ? a1 : al * a1;
        a2 = a2 >= 0.f ? a2 : al * a2;
        a3 = a3 >= 0.f ? a3 : al * a3;
    }
    if (OUT_F16) {
        half4 o;
        o.x = (_Float16)a0; o.y = (_Float16)a1; o.z = (_Float16)a2; o.w = (_Float16)a3;
        *(half4*)((_Float16*)out_mat + (size_t)wid * F_DIM + lo) = o;
    } else {
        float4 o = make_float4(a0, a1, a2, a3);
        *(float4*)((float*)out_mat + (size_t)wid * F_DIM + lo) = o;
    }
}

// ---------------------------------------------------------------------------
extern "C" void kernel_launch(void* const* d_in, const int* in_sizes, int n_in,
                              void* d_out, int out_size, void* d_ws, size_t ws_size,
                              hipStream_t stream) {
    const float* x   = (const float*)d_in[0];
    const int*   ei  = (const int*)d_in[1];
    const float* W1  = (const float*)d_in[2];
    const float* b1  = (const float*)d_in[3];
    const float* W2  = (const float*)d_in[4];
    const float* b2  = (const float*)d_in[5];
    const float* a   = (const float*)d_in[6];
    float* out = (float*)d_out;

    const int M   = in_sizes[0] / F_DIM;   // 100000
    const int nnz = in_sizes[1] / 2;       // 1600000
    const int* src = ei;
    const int* dst = ei + nnz;

    const int NB = (M + (1 << BW_SHIFT) - 1) >> BW_SHIFT;              // 196
    const int avg = (int)(((long long)nnz << BW_SHIFT) / M);           // ~8192
    const int BUCKCAP = avg + avg / 8 + 256;                           // ~9472 (+14 sigma)
    const int nchunks = (nnz + CHUNK - 1) / CHUNK;

    char* p = (char*)d_ws;
    const size_t nbuf   = (size_t)M * F_DIM * sizeof(float);      // 102.4 MB
    const size_t nbuf16 = (size_t)M * F_DIM * sizeof(_Float16);   // 51.2 MB
    const size_t wpk    = 8 * 16 * 64 * 8 * sizeof(short);        // 128 KB
    float*    bufH  = (float*)p;           p += nbuf;     // h (f32); part aliases
    _Float16* bufXT = (_Float16*)p;        p += nbuf16;   // xt (f16)
    _Float16* bufM  = (_Float16*)p;        p += nbuf16;   // m  (f16)
    short* W1hi = (short*)p;               p += wpk;
    short* W1lo = (short*)p;               p += wpk;
    short* W2hi = (short*)p;               p += wpk;
    short* W2lo = (short*)p;               p += wpk;
    int* adjS   = (int*)p;                 p += (size_t)M * CAP * 4;   // 19.2 MB
    int* adjD   = (int*)p;                 p += (size_t)M * CAP * 4;
    int* degS   = (int*)p;                 p += (size_t)M * 4;
    int* degD   = (int*)p;                 p += (size_t)M * 4;
    float* Dinv = (float*)p;               p += (size_t)M * 4;
    float* Binv = (float*)p;               p += (size_t)M * 4;
    int* bucketCur = (int*)p;              p += ((size_t)2 * NB * 4 + 15) & ~15ull;

    // partition scratch aliases bufH: dead before g2 writes bufH.
    // size = 2*NB*BUCKCAP*4 ~ 14.9 MB <= 102.4 MB.
    unsigned* part = (unsigned*)bufH;

    const dim3 blk(256);
    const dim3 gemm_grid((M + 127) / 128);
    const int gather_blocks = (M + 3) / 4;

    // ---- adjacency build (zero per-edge global atomics) ----
    init_cur_kernel<<<(2 * NB + 255) / 256, blk, 0, stream>>>(bucketCur, 2 * NB, BUCKCAP);
    partition_kernel<<<dim3(nchunks, 2), blk, 0, stream>>>(src, dst, part, bucketCur,
                                                           nnz, NB, BUCKCAP);
    bucket_fill_kernel<<<dim3(NB, 2), blk, 0, stream>>>(part, bucketCur, adjS, adjD,
                                                        degS, degD, Dinv, Binv,
                                                        M, NB, BUCKCAP);

    // ---- weight prepack (hi/lo) ----
    prepack_w_kernel<<<dim3(16, 8), 64, 0, stream>>>(W1, W1hi, W1lo);
    prepack_w_kernel<<<dim3(16, 8), 64, 0, stream>>>(W2, W2hi, W2lo);

    // ---- conv1 ----
    gemm_mfma_split<<<gemm_grid, blk, 0, stream>>>(x, W1hi, W1lo, bufXT, M);       // xt (f16)
    gather_rows_kernel<1><<<gather_blocks, blk, 0, stream>>>(bufXT, bufM, degD, adjD,
                                                             Binv, nullptr, nullptr, nullptr, M); // m (f16)
    gather_rows_kernel<0><<<gather_blocks, blk, 0, stream>>>(bufM, bufH, degS, adjS,
                                                             Dinv, b1, nullptr, a, M);            // h (f32)
    // ---- conv2 ----
    gemm_mfma_split<<<gemm_grid, blk, 0, stream>>>(bufH, W2hi, W2lo, bufXT, M);    // xt2 (f16)
    gather_rows_kernel<1><<<gather_blocks, blk, 0, stream>>>(bufXT, bufM, degD, adjD,
                                                             Binv, nullptr, nullptr, nullptr, M); // m2 (f16)
    gather_rows_kernel<0><<<gather_blocks, blk, 0, stream>>>(bufM, out, degS, adjS,
                                                             Dinv, b2, x, a, M);                  // prelu(.+x)
}

// Round 5
// 900.927 us; speedup vs baseline: 1.0179x; 1.0179x over previous
//
#include <hip/hip_runtime.h>
#include <hip/hip_bf16.h>

// ---------------------------------------------------------------------------
// HypergraphConv x2 + PReLU + residual. R9: barrier-free direct-load GEMM +
// f16 h + partition bucket-byte.
//   R8 post-mortem: GEMM A-dedup was null -> A re-read was L2-absorbed; the
//   GEMM cost is its 2-barrier-per-K-tile LDS staging (roofline ~30us vs
//   ~90us measured). R9 GEMM: no LDS, no barriers - A fragments loaded
//   straight from global (coalesced 128B row segments), f32->bf16 hi/lo
//   split in-reg, 3 MFMAs per tile. h stored f16 (exact 8+3 split for
//   GEMM2). Partition writeout uses staged bucket-id byte (no bin-search).
// Gathers unchanged: 433MB fetch = 8-XCD compulsory floor.
// ---------------------------------------------------------------------------

#define F_DIM 256
#define CAP 48          // padded adjacency slots per node; P(deg>=48)~1e-10
#define BW_SHIFT 9      // bucket width 512 nodes
#define CHUNK 2048      // edges per partition block

using bf16x8 = __attribute__((ext_vector_type(8))) short;
using f32x4  = __attribute__((ext_vector_type(4))) float;
using half4  = __attribute__((ext_vector_type(4))) _Float16;
using half8  = __attribute__((ext_vector_type(8))) _Float16;

__device__ __forceinline__ short f2bf(float f) {
    __hip_bfloat16 h = __float2bfloat16(f);
    return *reinterpret_cast<short*>(&h);
}
__device__ __forceinline__ float bf2f(short s) {
    return __uint_as_float(((unsigned)(unsigned short)s) << 16);
}

// ---- 1. bucket cursor init -------------------------------------------------
__global__ void init_cur_kernel(int* __restrict__ cur, int n, int buckcap) {
    int i = blockIdx.x * blockDim.x + threadIdx.x;
    if (i < n) cur[i] = i * buckcap;
}

// ---- 2. partition: edges -> bucket-grouped packed (key|val) ----------------
// grid (nchunks, 2): dir 0 keys=src (for adjS/degS), dir 1 keys=dst.
// entry = (val << 9) | (key & 511); val < 2^17, key&511 recovered in fill.
__global__ __launch_bounds__(256) void partition_kernel(
    const int* __restrict__ src, const int* __restrict__ dst,
    unsigned* __restrict__ part, int* __restrict__ cur,
    int nnz, int nb, int buckcap)
{
    __shared__ int lhist[256];
    __shared__ int lscan[256];
    __shared__ int gbase[256];
    __shared__ int sh_total;
    __shared__ unsigned lstage[CHUNK];        // 8 KB
    __shared__ unsigned char lbuck[CHUNK];    // 2 KB: bucket id per staged entry

    const int tid = threadIdx.x;
    const int dir = blockIdx.y;
    const int base = blockIdx.x * CHUNK;
    const int* __restrict__ key = dir ? dst : src;
    const int* __restrict__ val = dir ? src : dst;

    lhist[tid] = 0;
    __syncthreads();

    int myb[8], myr[8];
    unsigned mye[8];
#pragma unroll
    for (int i = 0; i < 8; ++i) {
        int g = base + tid + i * 256;
        myb[i] = -1;
        if (g < nnz) {
            int k = key[g];
            mye[i] = ((unsigned)val[g] << 9) | (unsigned)(k & 511);
            myb[i] = k >> BW_SHIFT;
            myr[i] = atomicAdd(&lhist[myb[i]], 1);   // LDS atomic: rank in block
        }
    }
    __syncthreads();

    // inclusive scan of per-bucket counts (Hillis-Steele over 256 bins)
    int v0 = lhist[tid];
    lscan[tid] = v0;
    __syncthreads();
    for (int off = 1; off < 256; off <<= 1) {
        int add = (tid >= off) ? lscan[tid - off] : 0;
        __syncthreads();
        lscan[tid] += add;
        __syncthreads();
    }
    int incl = lscan[tid];
    if (tid == 255) sh_total = incl;
    // reserve global space: one atomic per non-empty bucket per block
    if (tid < nb && v0 > 0) gbase[tid] = atomicAdd(&cur[dir * nb + tid], v0);
    __syncthreads();
    lscan[tid] = incl - v0;          // exclusive
    __syncthreads();

    // stage sorted-by-bucket in LDS; record bucket id per slot
#pragma unroll
    for (int i = 0; i < 8; ++i)
        if (myb[i] >= 0) {
            int pos = lscan[myb[i]] + myr[i];
            lstage[pos] = mye[i];
            lbuck[pos] = (unsigned char)myb[i];
        }
    __syncthreads();

    // write out bucket runs (consecutive k -> consecutive dest = coalesced)
    const int total = sh_total;
    for (int k = tid; k < total; k += 256) {
        int b = lbuck[k];
        int pos = gbase[b] + (k - lscan[b]);
        if (pos < (dir * nb + b + 1) * buckcap)   // overflow guard (never fires)
            part[pos] = lstage[k];
    }
}

// ---- 3. per-bucket fill: LDS per-node counters, L2-local adj writes --------
//         also emits deg[] and inverse-degree (Dinv/Binv) directly.
__global__ __launch_bounds__(256) void bucket_fill_kernel(
    const unsigned* __restrict__ part, const int* __restrict__ cur,
    int* __restrict__ adjS, int* __restrict__ adjD,
    int* __restrict__ degS, int* __restrict__ degD,
    float* __restrict__ Dinv, float* __restrict__ Binv,
    int M, int nb, int buckcap)
{
    __shared__ int lcnt[512];
    const int tid = threadIdx.x;
    const int b = blockIdx.x;
    const int dir = blockIdx.y;
    const int c = dir * nb + b;
    int* __restrict__ adj = dir ? adjD : adjS;
    int* __restrict__ deg = dir ? degD : degS;
    float* __restrict__ inv = dir ? Binv : Dinv;

    lcnt[tid] = 0;
    lcnt[tid + 256] = 0;
    __syncthreads();

    const int pbase = c * buckcap;
    const int cnt = min(cur[c] - pbase, buckcap);
    const int node0 = b << BW_SHIFT;
    for (int i = tid; i < cnt; i += 256) {
        unsigned e = part[pbase + i];
        int klocal = (int)(e & 511u);
        int v = (int)(e >> 9);
        int r = atomicAdd(&lcnt[klocal], 1);    // LDS atomic
        if (r < CAP) adj[(size_t)(node0 + klocal) * CAP + r] = v;
    }
    __syncthreads();
    for (int i = tid; i < 512; i += 256) {
        int node = node0 + i;
        if (node < M) {
            int d = min(lcnt[i], CAP);
            deg[node] = d;
            inv[node] = d > 0 ? 1.f / (float)d : 0.f;
        }
    }
}

// ---- 4. W prepack: f32 -> bf16 hi/lo MFMA B-fragment order -----------------
// frag blob (kt,nt): 64 lanes x 8; lane holds B[kt*32+(lane>>4)*8+j][nt*16+(lane&15)]
__global__ void prepack_w_kernel(const float* __restrict__ W,
                                 short* __restrict__ Whi, short* __restrict__ Wlo) {
    int lane = threadIdx.x;            // 64
    int nt = blockIdx.x;               // 16
    int kt = blockIdx.y;               // 8
    int col = nt * 16 + (lane & 15);
    int krow = kt * 32 + (lane >> 4) * 8;
    size_t o = ((size_t)(kt * 16 + nt) * 64 + lane) * 8;
#pragma unroll
    for (int j = 0; j < 8; ++j) {
        float w = W[(size_t)(krow + j) * 256 + col];
        short hi = f2bf(w);
        Whi[o + j] = hi;
        Wlo[o + j] = f2bf(w - bf2f(hi));
    }
}

// ---- 5. barrier-free split-bf16 MFMA GEMM: C[M,256](f16) = A @ W -----------
// No LDS: A fragments loaded directly from global. Lane l16 holds row
// bm+wm+i*16+l16, k-slice kt*32+quad*8..+8 (8 contiguous elems). A wave's
// 64 lanes read 16 rows x 128B contiguous segments -> coalesced; the 2x
// wave/block overlap on A rows is L1/L2-absorbed.
// block 256 thr = 4 waves (2 in M x 2 in N); grid (M/128, 2); wave 64x64.
template <typename AT>
__global__ __launch_bounds__(256) void gemm_direct(const AT* __restrict__ A,
                                                   const short* __restrict__ Whi,
                                                   const short* __restrict__ Wlo,
                                                   _Float16* __restrict__ C, int M) {
    const int tid = threadIdx.x;
    const int w = tid >> 6, lane = tid & 63;
    const int quad = lane >> 4, l16 = lane & 15;
    const int bm = blockIdx.x * 128;
    const int bn_t = blockIdx.y * 8;             // n-tile base (16-col tiles)
    const int wm = (w & 1) * 64;
    const int wnt = (w >> 1) * 4;

    f32x4 acc[4][4] = {};

#pragma unroll
    for (int kt = 0; kt < 8; ++kt) {
        bf16x8 ahi[4], alo[4];
#pragma unroll
        for (int i = 0; i < 4; ++i) {
            int row = bm + wm + i * 16 + l16;
            if (row >= M) row = M - 1;
            const AT* ap = A + (size_t)row * 256 + kt * 32 + quad * 8;
            float vv[8];
            if constexpr (sizeof(AT) == 4) {
                float4 v0 = *(const float4*)ap;
                float4 v1 = *(const float4*)(ap + 4);
                vv[0] = v0.x; vv[1] = v0.y; vv[2] = v0.z; vv[3] = v0.w;
                vv[4] = v1.x; vv[5] = v1.y; vv[6] = v1.z; vv[7] = v1.w;
            } else {
                half8 v = *(const half8*)ap;
#pragma unroll
                for (int e = 0; e < 8; ++e) vv[e] = (float)v[e];
            }
#pragma unroll
            for (int e = 0; e < 8; ++e) {
                short hi = f2bf(vv[e]);
                ahi[i][e] = hi;
                alo[i][e] = f2bf(vv[e] - bf2f(hi));
            }
        }

#pragma unroll
        for (int j = 0; j < 4; ++j) {
            int nt = bn_t + wnt + j;
            size_t off = ((size_t)(kt * 16 + nt) * 64 + lane) * 8;
            bf16x8 bhi = *(const bf16x8*)(Whi + off);
            bf16x8 blo = *(const bf16x8*)(Wlo + off);
#pragma unroll
            for (int i = 0; i < 4; ++i) {
                acc[i][j] = __builtin_amdgcn_mfma_f32_16x16x32_bf16(ahi[i], bhi, acc[i][j], 0, 0, 0);
                acc[i][j] = __builtin_amdgcn_mfma_f32_16x16x32_bf16(ahi[i], blo, acc[i][j], 0, 0, 0);
                acc[i][j] = __builtin_amdgcn_mfma_f32_16x16x32_bf16(alo[i], bhi, acc[i][j], 0, 0, 0);
            }
        }
    }

    // epilogue: C[row][col] = (f16)acc; row = wm + i*16 + quad*4 + r
#pragma unroll
    for (int i = 0; i < 4; ++i) {
#pragma unroll
        for (int j = 0; j < 4; ++j) {
            int col = (bn_t + wnt + j) * 16 + l16;
            int row0 = bm + wm + i * 16 + quad * 4;
#pragma unroll
            for (int r = 0; r < 4; ++r) {
                int row = row0 + r;
                if (row < M) C[(size_t)row * 256 + col] = (_Float16)acc[i][j][r];
            }
        }
    }
}

// ---- 6. pull gather: out[r] = f(scale[r]*sum_{j in adj[r]} src[j]) ---------
// src rows are f16 (512B). padded adjacency: row r at adj[r*CAP .. +deg[r]).
// OUT_F16=1 -> f16 output; OUT_F16=0 -> f32 output (final only).
template <int OUT_F16>
__global__ __launch_bounds__(256) void gather_rows_kernel(const _Float16* __restrict__ src_mat,
                                                          void* __restrict__ out_mat,
                                                          const int* __restrict__ deg,
                                                          const int* __restrict__ adj,
                                                          const float* __restrict__ scale,
                                                          const float* __restrict__ bias,
                                                          const float* __restrict__ residual,
                                                          const float* __restrict__ alpha_p,
                                                          int n) {
    int wid = (blockIdx.x * blockDim.x + threadIdx.x) >> 6;
    int lane = threadIdx.x & 63;
    if (wid >= n) return;
    const int dcount = deg[wid];                      // <= CAP (48) < 64
    const int* arow = adj + (size_t)wid * CAP;
    int myidx = (lane < dcount) ? __builtin_nontemporal_load(arow + lane) : 0;

    const size_t lo = (size_t)lane * 4;               // 4 f16 elems = 8B per lane
    float a0 = 0.f, a1 = 0.f, a2 = 0.f, a3 = 0.f;

    for (int j = 0; j < dcount; ++j) {
        int idx = __shfl(myidx, j);
        half4 v = *(const half4*)(src_mat + (size_t)idx * F_DIM + lo);
        a0 += (float)v.x; a1 += (float)v.y; a2 += (float)v.z; a3 += (float)v.w;
    }

    float sc = scale[wid];
    a0 *= sc; a1 *= sc; a2 *= sc; a3 *= sc;
    if (bias) {
        float4 bb = ((const float4*)bias)[lane];
        a0 += bb.x; a1 += bb.y; a2 += bb.z; a3 += bb.w;
    }
    if (residual) {
        const float* rp = residual + (size_t)wid * F_DIM + lo;
        float4 xv;
        xv.x = __builtin_nontemporal_load(rp + 0);
        xv.y = __builtin_nontemporal_load(rp + 1);
        xv.z = __builtin_nontemporal_load(rp + 2);
        xv.w = __builtin_nontemporal_load(rp + 3);
        a0 += xv.x; a1 += xv.y; a2 += xv.z; a3 += xv.w;
    }
    if (alpha_p) {
        float al = alpha_p[0];
        a0 = a0 >= 0.f ? a0 : al * a0;
        a1 = a1 >= 0.f ? a1 : al * a1;
        a2 = a2 >= 0.f ? a2 : al * a2;
        a3 = a3 >= 0.f ? a3 : al * a3;
    }
    if (OUT_F16) {
        half4 o;
        o.x = (_Float16)a0; o.y = (_Float16)a1; o.z = (_Float16)a2; o.w = (_Float16)a3;
        *(half4*)((_Float16*)out_mat + (size_t)wid * F_DIM + lo) = o;
    } else {
        float4 o = make_float4(a0, a1, a2, a3);
        *(float4*)((float*)out_mat + (size_t)wid * F_DIM + lo) = o;
    }
}

// ---------------------------------------------------------------------------
extern "C" void kernel_launch(void* const* d_in, const int* in_sizes, int n_in,
                              void* d_out, int out_size, void* d_ws, size_t ws_size,
                              hipStream_t stream) {
    const float* x   = (const float*)d_in[0];
    const int*   ei  = (const int*)d_in[1];
    const float* W1  = (const float*)d_in[2];
    const float* b1  = (const float*)d_in[3];
    const float* W2  = (const float*)d_in[4];
    const float* b2  = (const float*)d_in[5];
    const float* a   = (const float*)d_in[6];
    float* out = (float*)d_out;

    const int M   = in_sizes[0] / F_DIM;   // 100000
    const int nnz = in_sizes[1] / 2;       // 1600000
    const int* src = ei;
    const int* dst = ei + nnz;

    const int NB = (M + (1 << BW_SHIFT) - 1) >> BW_SHIFT;              // 196
    const int avg = (int)(((long long)nnz << BW_SHIFT) / M);           // ~8192
    const int BUCKCAP = avg + avg / 8 + 256;                           // ~9472 (+14 sigma)
    const int nchunks = (nnz + CHUNK - 1) / CHUNK;

    char* p = (char*)d_ws;
    const size_t nbuf   = (size_t)M * F_DIM * sizeof(float);      // 102.4 MB
    const size_t nbuf16 = (size_t)M * F_DIM * sizeof(_Float16);   // 51.2 MB
    const size_t wpk    = 8 * 16 * 64 * 8 * sizeof(short);        // 128 KB
    _Float16* bufH  = (_Float16*)p;        p += nbuf;     // h (f16); part aliases
    _Float16* bufXT = (_Float16*)p;        p += nbuf16;   // xt (f16)
    _Float16* bufM  = (_Float16*)p;        p += nbuf16;   // m  (f16)
    short* W1hi = (short*)p;               p += wpk;
    short* W1lo = (short*)p;               p += wpk;
    short* W2hi = (short*)p;               p += wpk;
    short* W2lo = (short*)p;               p += wpk;
    int* adjS   = (int*)p;                 p += (size_t)M * CAP * 4;   // 19.2 MB
    int* adjD   = (int*)p;                 p += (size_t)M * CAP * 4;
    int* degS   = (int*)p;                 p += (size_t)M * 4;
    int* degD   = (int*)p;                 p += (size_t)M * 4;
    float* Dinv = (float*)p;               p += (size_t)M * 4;
    float* Binv = (float*)p;               p += (size_t)M * 4;
    int* bucketCur = (int*)p;              p += ((size_t)2 * NB * 4 + 15) & ~15ull;

    // partition scratch aliases bufH: dead before the conv1 h-gather writes it.
    // size = 2*NB*BUCKCAP*4 ~ 14.9 MB <= 102.4 MB region.
    unsigned* part = (unsigned*)bufH;

    const dim3 blk(256);
    const dim3 gemm_grid((M + 127) / 128, 2);
    const int gather_blocks = (M + 3) / 4;

    // ---- adjacency build (zero per-edge global atomics) ----
    init_cur_kernel<<<(2 * NB + 255) / 256, blk, 0, stream>>>(bucketCur, 2 * NB, BUCKCAP);
    partition_kernel<<<dim3(nchunks, 2), blk, 0, stream>>>(src, dst, part, bucketCur,
                                                           nnz, NB, BUCKCAP);
    bucket_fill_kernel<<<dim3(NB, 2), blk, 0, stream>>>(part, bucketCur, adjS, adjD,
                                                        degS, degD, Dinv, Binv,
                                                        M, NB, BUCKCAP);

    // ---- weight prepack (hi/lo) ----
    prepack_w_kernel<<<dim3(16, 8), 64, 0, stream>>>(W1, W1hi, W1lo);
    prepack_w_kernel<<<dim3(16, 8), 64, 0, stream>>>(W2, W2hi, W2lo);

    // ---- conv1 ----
    gemm_direct<float><<<gemm_grid, blk, 0, stream>>>(x, W1hi, W1lo, bufXT, M);    // xt (f16)
    gather_rows_kernel<1><<<gather_blocks, blk, 0, stream>>>(bufXT, bufM, degD, adjD,
                                                             Binv, nullptr, nullptr, nullptr, M); // m (f16)
    gather_rows_kernel<1><<<gather_blocks, blk, 0, stream>>>(bufM, bufH, degS, adjS,
                                                             Dinv, b1, nullptr, a, M);            // h (f16)
    // ---- conv2 ----
    gemm_direct<_Float16><<<gemm_grid, blk, 0, stream>>>(bufH, W2hi, W2lo, bufXT, M); // xt2 (f16)
    gather_rows_kernel<1><<<gather_blocks, blk, 0, stream>>>(bufXT, bufM, degD, adjD,
                                                             Binv, nullptr, nullptr, nullptr, M); // m2 (f16)
    gather_rows_kernel<0><<<gather_blocks, blk, 0, stream>>>(bufM, out, degS, adjS,
                                                             Dinv, b2, x, a, M);                  // prelu(.+x)
}